// Round 3
// baseline (173.717 us; speedup 1.0000x reference)
//
#include <hip/hip_runtime.h>
#include <hip/hip_bf16.h>

typedef __attribute__((ext_vector_type(8))) short short8;
typedef __attribute__((ext_vector_type(4))) float f32x4;

#define D_MODEL 512
#define BN 128
#define NT 16
#define A_TILE 16384   // 256 rows x 64B (bf16 k-slice of 32)
#define B_TILE 8192    // 128 rows x 64B (bf16 k-slice of 32)

__device__ __forceinline__ void gload16(const void* g, void* l) {
    typedef const __attribute__((address_space(1))) unsigned GT;
    typedef __attribute__((address_space(3))) unsigned LT;
    __builtin_amdgcn_global_load_lds((GT*)g, (LT*)l, 16, 0, 0);
}

__device__ __forceinline__ short f2bf(float f) {
    unsigned u = __builtin_bit_cast(unsigned, f);
    unsigned r = (u + 0x7fffu + ((u >> 16) & 1u)) >> 16;
    return (short)r;
}

__device__ __forceinline__ short8 cvt8(const float4& a, const float4& b) {
    union { __hip_bfloat162 h[4]; short8 s; } u;
    u.h[0] = __float22bfloat162_rn(make_float2(a.x, a.y));
    u.h[1] = __float22bfloat162_rn(make_float2(a.z, a.w));
    u.h[2] = __float22bfloat162_rn(make_float2(b.x, b.y));
    u.h[3] = __float22bfloat162_rn(make_float2(b.z, b.w));
    return u.s;
}
__device__ __forceinline__ float ssq(const float4& a, const float4& b) {
    return a.x*a.x + a.y*a.y + a.z*a.z + a.w*a.w
         + b.x*b.x + b.y*b.y + b.z*b.z + b.w*b.w;
}

// Kernel 1: cond[b][k] = ent[s_ent[b]][k] + rel[relation[b]][k]  (bf16 -> ws), a2[b] = ||cond||^2
__global__ void prep_kernel(const int* __restrict__ s_ent, const int* __restrict__ rel,
                            const float* __restrict__ ent, const float* __restrict__ relemb,
                            short* __restrict__ condb, float* __restrict__ a2) {
    const int b = blockIdx.x;
    const int t = threadIdx.x;
    const float4 v = *(const float4*)(ent + (size_t)s_ent[b] * D_MODEL + t * 4);
    const float4 w = *(const float4*)(relemb + (size_t)rel[b] * D_MODEL + t * 4);
    float c0 = v.x + w.x, c1 = v.y + w.y, c2 = v.z + w.z, c3 = v.w + w.w;
    float sq = c0 * c0 + c1 * c1 + c2 * c2 + c3 * c3;

    short4 s;
    s.x = f2bf(c0); s.y = f2bf(c1); s.z = f2bf(c2); s.w = f2bf(c3);
    *(short4*)(condb + (size_t)b * D_MODEL + t * 4) = s;

    #pragma unroll
    for (int off = 1; off < 64; off <<= 1) sq += __shfl_xor(sq, off);
    __shared__ float red[2];
    if ((t & 63) == 0) red[t >> 6] = sq;
    __syncthreads();
    if (t == 0) a2[b] = red[0] + red[1];
}

// Kernel 2: BM=256, BN=128, BK=32, 512 thr = 8 waves (4M x 2N).
// A (bf16) gload_lds ring-2, source-swizzled; B reg-staged fp32 -> cvt once -> bf16 LDS ring-2.
// One s_barrier + vmcnt(0)/lgkmcnt(0) per K-step; all prefetch issued post-barrier (1-iter budget).
__global__ __launch_bounds__(512, 4)
void score_kernel(const float* __restrict__ ent, const short* __restrict__ condb,
                  const float* __restrict__ a2, float* __restrict__ out, const int n_ent) {
    __shared__ __align__(16) unsigned char lds[2 * A_TILE + 2 * B_TILE];  // 48 KiB
    unsigned char* Al = lds;
    unsigned char* Bl = lds + 2 * A_TILE;

    const int tid  = threadIdx.x;
    const int lane = tid & 63;
    const int w    = tid >> 6, wm = w >> 1, wn = w & 1;
    const int lrow = lane & 15, g4 = lane >> 4;
    const int nbase = blockIdx.x * BN;

    // A staging: LDS linear at tid*16 (+8192); XOR-swizzle applied on the GLOBAL source (rule #21)
    const int p0 = tid * 16, p1 = p0 + 8192;
    const int ar0 = p0 >> 6, ar1 = p1 >> 6;
    const char* gA0 = (const char*)condb + ar0 * 1024 + ((p0 & 63) ^ ((ar0 & 3) << 4));
    const char* gA1 = (const char*)condb + ar1 * 1024 + ((p1 & 63) ^ ((ar1 & 3) << 4));

    // B staging: thread owns (row sr, 8-float slot sk); ds_write bf16 with same swizzle family
    const int sr = tid >> 2, sk = (tid & 3) * 8;
    const long long gr = min((long long)(nbase + sr), (long long)(n_ent - 1));  // clamp tail
    const float* gB = ent + gr * D_MODEL + sk;
    const int bwoff = sr * 64 + ((sk * 2) ^ ((sr & 3) << 4));

    // fragment read offsets: swizzle depends only on lrow&3 -> single base + f*1024 immediates
    const int base_a = (wm * 64 + lrow) * 64 + ((g4 * 16) ^ ((lrow & 3) << 4));
    const int base_b = (wn * 64 + lrow) * 64 + ((g4 * 16) ^ ((lrow & 3) << 4));

    f32x4 acc[4][4] = {};
    float sq = 0.f;

    // prologue: B(0)->rbA, B(1)->rbB, A(0)->Al[0]; stage B(0) into Bl[0]
    float4 rbA0 = *(const float4*)(gB);
    float4 rbA1 = *(const float4*)(gB + 4);
    float4 rbB0 = *(const float4*)(gB + 32);
    float4 rbB1 = *(const float4*)(gB + 36);
    gload16(gA0, Al + p0);
    gload16(gA1, Al + p1);
    sq += ssq(rbA0, rbA1);
    *(short8*)(Bl + bwoff) = cvt8(rbA0, rbA1);

#define KSTEP(T, CV0, CV1, LD0, LD1, DO_CVT, DO_LDB, DO_LDA)                              \
  {                                                                                        \
    asm volatile("s_waitcnt vmcnt(0)" ::: "memory");                                       \
    short8 cb;                                                                             \
    if (DO_CVT) { sq += ssq(CV0, CV1); cb = cvt8(CV0, CV1); }                              \
    asm volatile("s_waitcnt lgkmcnt(0)" ::: "memory");                                     \
    __builtin_amdgcn_s_barrier();                                                          \
    if (DO_LDB) { LD0 = *(const float4*)(gB + ((T) + 2) * 32);                             \
                  LD1 = *(const float4*)(gB + ((T) + 2) * 32 + 4); }                       \
    if (DO_LDA) { unsigned char* ad = Al + (((T) + 1) & 1) * A_TILE;                       \
                  gload16(gA0 + ((T) + 1) * 64, ad + p0);                                  \
                  gload16(gA1 + ((T) + 1) * 64, ad + p1); }                                \
    if (DO_CVT) *(short8*)(Bl + (((T) + 1) & 1) * B_TILE + bwoff) = cb;                    \
    const unsigned char* ab = Al + ((T) & 1) * A_TILE;                                     \
    const unsigned char* bb = Bl + ((T) & 1) * B_TILE;                                     \
    short8 af0 = *(const short8*)(ab + base_a);                                            \
    short8 af1 = *(const short8*)(ab + base_a + 1024);                                     \
    short8 af2 = *(const short8*)(ab + base_a + 2048);                                     \
    short8 af3 = *(const short8*)(ab + base_a + 3072);                                     \
    _Pragma("unroll")                                                                      \
    for (int fn = 0; fn < 4; ++fn) {                                                       \
      short8 bf = *(const short8*)(bb + base_b + fn * 1024);                               \
      acc[0][fn] = __builtin_amdgcn_mfma_f32_16x16x32_bf16(af0, bf, acc[0][fn], 0, 0, 0);  \
      acc[1][fn] = __builtin_amdgcn_mfma_f32_16x16x32_bf16(af1, bf, acc[1][fn], 0, 0, 0);  \
      acc[2][fn] = __builtin_amdgcn_mfma_f32_16x16x32_bf16(af2, bf, acc[2][fn], 0, 0, 0);  \
      acc[3][fn] = __builtin_amdgcn_mfma_f32_16x16x32_bf16(af3, bf, acc[3][fn], 0, 0, 0);  \
    }                                                                                      \
  }

    // steady state: t = 0..13 (even: cvt B(t+1) from rbB, load B(t+2) -> rbA; odd: swapped)
    for (int tt = 0; tt < 14; tt += 2) {
        KSTEP(tt,     rbB0, rbB1, rbA0, rbA1, true,  true,  true)
        KSTEP(tt + 1, rbA0, rbA1, rbB0, rbB1, true,  true,  true)
    }
    // tail: t=14 (no B(16) load), t=15 (compute only)
    KSTEP(14, rbB0, rbB1, rbA0, rbA1, true,  false, true)
    KSTEP(15, rbA0, rbA1, rbB0, rbB1, false, false, false)
#undef KSTEP

    // b2[n]: each thread holds sum over its 128 staged cols of row sr; reduce 4 threads/row
    sq += __shfl_xor(sq, 1);
    sq += __shfl_xor(sq, 2);
    float* b2s = (float*)lds;   // A buf0 region, dead after t=14
    if ((tid & 3) == 0) b2s[sr] = sq;
    __syncthreads();

    // epilogue: d2 = a2[m] - 2*ab + b2[n]; score = -sqrt(max(d2, 1e-12))
    #pragma unroll
    for (int fm = 0; fm < 4; ++fm) {
        const int m0 = wm * 64 + fm * 16 + g4 * 4;
        const f32x4 a2v = *(const f32x4*)(a2 + m0);
        #pragma unroll
        for (int fn = 0; fn < 4; ++fn) {
            const int nl = wn * 64 + fn * 16 + lrow;
            const int ng = nbase + nl;
            if (ng < n_ent) {
                const float b2v = b2s[nl];
                #pragma unroll
                for (int r = 0; r < 4; ++r) {
                    float d2 = a2v[r] - 2.f * acc[fm][fn][r] + b2v;
                    out[(size_t)(m0 + r) * n_ent + ng] = -sqrtf(fmaxf(d2, 1e-12f));
                }
            }
        }
    }
}

extern "C" void kernel_launch(void* const* d_in, const int* in_sizes, int n_in,
                              void* d_out, int out_size, void* d_ws, size_t ws_size,
                              hipStream_t stream) {
    const int*   s_ent  = (const int*)d_in[0];
    const int*   rel    = (const int*)d_in[1];
    // d_in[2] = o_ent, d_in[3] = time : unused by reference forward
    const float* ent    = (const float*)d_in[4];
    const float* relemb = (const float*)d_in[5];
    float* out = (float*)d_out;

    const int bs    = in_sizes[0];              // 256
    const int n_ent = in_sizes[4] / D_MODEL;    // 200000

    short* condb = (short*)d_ws;                               // bs*512 bf16 = 256KB
    float* a2    = (float*)((char*)d_ws + (size_t)bs * D_MODEL * 2);

    prep_kernel<<<bs, 128, 0, stream>>>(s_ent, rel, ent, relemb, condb, a2);

    const int ntiles = (n_ent + BN - 1) / BN;   // 1563
    score_kernel<<<ntiles, 512, 0, stream>>>(ent, condb, a2, out, n_ent);
}